// Round 1
// baseline (434.509 us; speedup 1.0000x reference)
//
#include <hip/hip_runtime.h>
#include <math.h>

// RootMLP: per-sample MLP  1 -> 128 -> 128 -> 128 -> 128 -> 64
// head: mean = tanh(y[:32]), std = exp(0.5*clip(y[32:], -4, 4))
// flat_weights[b] layout per layer: W (d_out, d_in) row-major, then bias (d_out).

#define WIDTH 128
#define OUTD  64
#define L0_PARAMS 256                    // 128*1 + 128
#define HID_PARAMS (WIDTH*WIDTH + WIDTH) // 16512
#define TOTAL_PARAMS 58048

__device__ __forceinline__ float silu(float a) {
    // a * sigmoid(a); for a << 0, expf(-a) -> inf -> result -> 0 (correct limit)
    return a / (1.0f + expf(-a));
}

__global__ __launch_bounds__(128)
void rootmlp_kernel(const float* __restrict__ x,
                    const float* __restrict__ w,
                    float* __restrict__ out) {
    const int b = blockIdx.x;
    const int j = threadIdx.x;
    const float* __restrict__ wb = w + (size_t)b * TOTAL_PARAMS;

    __shared__ float y[WIDTH];

    // ---- layer 0: d_in = 1 ----
    {
        const float xv = x[b];
        float a = wb[j] * xv + wb[WIDTH + j];
        y[j] = silu(a);
    }
    __syncthreads();

    // ---- layers 1..3: 128 x 128, SiLU ----
    int idx = L0_PARAMS;
    #pragma unroll 1
    for (int l = 0; l < 3; ++l) {
        const float* __restrict__ W    = wb + idx;
        const float* __restrict__ bias = W + WIDTH * WIDTH;
        const float4* __restrict__ Wrow = (const float4*)(W + j * WIDTH);

        float a = bias[j];
        #pragma unroll
        for (int k4 = 0; k4 < WIDTH / 4; ++k4) {
            const float4 wv = Wrow[k4];
            a += wv.x * y[k4 * 4 + 0];
            a += wv.y * y[k4 * 4 + 1];
            a += wv.z * y[k4 * 4 + 2];
            a += wv.w * y[k4 * 4 + 3];
        }
        a = silu(a);
        __syncthreads();           // everyone done reading y
        y[j] = a;
        __syncthreads();           // y updated for next layer
        idx += HID_PARAMS;
    }

    // ---- layer 4: 128 -> 64, then heads ----
    if (j < OUTD) {
        const float* __restrict__ W    = wb + idx;
        const float* __restrict__ bias = W + OUTD * WIDTH;
        const float4* __restrict__ Wrow = (const float4*)(W + j * WIDTH);

        float a = bias[j];
        #pragma unroll
        for (int k4 = 0; k4 < WIDTH / 4; ++k4) {
            const float4 wv = Wrow[k4];
            a += wv.x * y[k4 * 4 + 0];
            a += wv.y * y[k4 * 4 + 1];
            a += wv.z * y[k4 * 4 + 2];
            a += wv.w * y[k4 * 4 + 3];
        }

        float r;
        if (j < 32) {
            r = tanhf(a);
        } else {
            float lv = fminf(fmaxf(a, -4.0f), 4.0f);
            r = expf(0.5f * lv);
        }
        out[(size_t)b * OUTD + j] = r;
    }
}

extern "C" void kernel_launch(void* const* d_in, const int* in_sizes, int n_in,
                              void* d_out, int out_size, void* d_ws, size_t ws_size,
                              hipStream_t stream) {
    const float* x = (const float*)d_in[0];        // (4096, 1)
    const float* w = (const float*)d_in[1];        // (4096, 58048)
    float* out = (float*)d_out;                    // (4096, 64)

    const int batch = in_sizes[0];                 // 4096
    rootmlp_kernel<<<batch, WIDTH, 0, stream>>>(x, w, out);
}

// Round 2
// 166.079 us; speedup vs baseline: 2.6163x; 2.6163x over previous
//
#include <hip/hip_runtime.h>
#include <math.h>

// RootMLP: per-sample MLP  1 -> 128 -> 128 -> 128 -> 128 -> 64
// head: mean = tanh(y[:32]), std = exp(0.5*clip(y[32:], -4, 4))
// flat_weights[b] layout per layer: W (d_out, d_in) row-major, then bias (d_out).
//
// Mapping: one block (256 thr) per sample. 8 lanes cooperate per output row:
// lane l reads float4 at row*512B + l*16 + i*128 -> each wave VMEM instruction
// covers exactly 8 FULL 128B cache lines (no fragmentation, no L1/L2 thrash).
// 3x shfl_xor reduces the 8 partials. Activations double-buffered in LDS
// (reads are same-address broadcasts across groups -> conflict-free).

#define WIDTH 128
#define OUTD  64
#define TOTAL_PARAMS 58048

__device__ __forceinline__ float silu(float a) {
    return a / (1.0f + expf(-a));
}

__global__ __launch_bounds__(256)
void rootmlp_kernel(const float* __restrict__ x,
                    const float* __restrict__ w,
                    float* __restrict__ out) {
    const int b = blockIdx.x;
    const int t = threadIdx.x;
    const int l = t & 7;    // lane within 8-lane group
    const int g = t >> 3;   // group id 0..31 (8 groups per wave)
    const float* __restrict__ wb = w + (size_t)b * TOTAL_PARAMS;

    __shared__ __align__(16) float ybuf[2][WIDTH];

    // ---- layer 0: 1 -> 128 (coalesced 1KB read) ----
    if (t < WIDTH) {
        float a = wb[t] * x[b] + wb[WIDTH + t];
        ybuf[0][t] = silu(a);
    }
    __syncthreads();

    int idx = 2 * WIDTH;
    int cur = 0;

    // ---- hidden layers 1..3: 128 x 128 + SiLU ----
    #pragma unroll 1
    for (int layer = 0; layer < 3; ++layer) {
        const float* __restrict__ W    = wb + idx;
        const float* __restrict__ bias = W + WIDTH * WIDTH;
        const float* __restrict__ ycur = ybuf[cur];

        #pragma unroll
        for (int p = 0; p < 4; ++p) {
            const int j = p * 32 + g;                       // output row
            const float4* __restrict__ Wrow = (const float4*)(W + j * WIDTH);
            float a = 0.0f;
            #pragma unroll
            for (int i = 0; i < 4; ++i) {
                const float4 wv = Wrow[l + i * 8];
                const float4 yv = *(const float4*)(ycur + l * 4 + i * 32);
                a += wv.x * yv.x + wv.y * yv.y + wv.z * yv.z + wv.w * yv.w;
            }
            a += __shfl_xor(a, 1);
            a += __shfl_xor(a, 2);
            a += __shfl_xor(a, 4);
            if (l == 0) {
                ybuf[cur ^ 1][j] = silu(a + bias[j]);
            }
        }
        __syncthreads();
        cur ^= 1;
        idx += WIDTH * WIDTH + WIDTH;
    }

    // ---- final layer: 128 -> 64, then heads ----
    {
        const float* __restrict__ W    = wb + idx;
        const float* __restrict__ bias = W + OUTD * WIDTH;
        const float* __restrict__ ycur = ybuf[cur];

        #pragma unroll
        for (int p = 0; p < 2; ++p) {
            const int j = p * 32 + g;
            const float4* __restrict__ Wrow = (const float4*)(W + j * WIDTH);
            float a = 0.0f;
            #pragma unroll
            for (int i = 0; i < 4; ++i) {
                const float4 wv = Wrow[l + i * 8];
                const float4 yv = *(const float4*)(ycur + l * 4 + i * 32);
                a += wv.x * yv.x + wv.y * yv.y + wv.z * yv.z + wv.w * yv.w;
            }
            a += __shfl_xor(a, 1);
            a += __shfl_xor(a, 2);
            a += __shfl_xor(a, 4);
            if (l == 0) {
                a += bias[j];
                float r;
                if (j < 32) {
                    r = tanhf(a);
                } else {
                    float lv = fminf(fmaxf(a, -4.0f), 4.0f);
                    r = expf(0.5f * lv);
                }
                out[(size_t)b * OUTD + j] = r;
            }
        }
    }
}

extern "C" void kernel_launch(void* const* d_in, const int* in_sizes, int n_in,
                              void* d_out, int out_size, void* d_ws, size_t ws_size,
                              hipStream_t stream) {
    const float* x = (const float*)d_in[0];        // (4096, 1)
    const float* w = (const float*)d_in[1];        // (4096, 58048)
    float* out = (float*)d_out;                    // (4096, 64)

    const int batch = in_sizes[0];                 // 4096
    rootmlp_kernel<<<batch, 256, 0, stream>>>(x, w, out);
}

// Round 3
// 163.626 us; speedup vs baseline: 2.6555x; 1.0150x over previous
//
#include <hip/hip_runtime.h>
#include <math.h>

// RootMLP: per-sample MLP  1 -> 128 -> 128 -> 128 -> 128 -> 64
// head: mean = tanh(y[:32]), std = exp(0.5*clip(y[32:], -4, 4))
// flat_weights[b] layout per layer: W (d_out, d_in) row-major, then bias (d_out).
//
// Round-3 structure: ONE WAVE per sample (4 waves/block, zero inter-wave
// communication). No __syncthreads() anywhere -> no vmcnt(0) drains; the
// VMEM stream of weight loads flows continuously across layer boundaries.
// Per-wave LDS y double-buffer ordered by s_waitcnt lgkmcnt(0) only
// (per-wave DS ops are processed in order; lgkmcnt(0) retires writes).
//
// Geometry (kept from round 2, the cache-line win): 8 lanes per output row;
// lane l reads float4 at row*512B + l*16 + i*128 -> every wave VMEM
// instruction covers full 128B cache lines only. 3x shfl_xor reduces the
// 8 partials. LDS y reads are same-address broadcasts across the 8 groups
// (conflict-free); writes are 8 consecutive floats (conflict-free).

#define WIDTH 128
#define OUTD  64
#define TOTAL_PARAMS 58048

__device__ __forceinline__ float silu(float a) {
    return a / (1.0f + expf(-a));
}

// Per-wave LDS write->read ordering fence. Does NOT touch vmcnt: outstanding
// global weight loads stay in flight across layer boundaries.
__device__ __forceinline__ void lds_fence() {
    asm volatile("s_waitcnt lgkmcnt(0)" ::: "memory");
}

__global__ __launch_bounds__(256, 4)   // cap VGPR at 128 so 4 blocks/CU resident
void rootmlp_kernel(const float* __restrict__ x,
                    const float* __restrict__ w,
                    float* __restrict__ out) {
    const int wv   = threadIdx.x >> 6;   // wave id 0..3 (one sample each)
    const int lane = threadIdx.x & 63;
    const int b    = blockIdx.x * 4 + wv;
    const int l    = lane & 7;           // lane within 8-lane group
    const int g    = lane >> 3;          // group id 0..7
    const float* __restrict__ wb = w + (size_t)b * TOTAL_PARAMS;

    __shared__ __align__(16) float ybuf[4][2][WIDTH];
    float (*yb)[WIDTH] = ybuf[wv];       // this wave's private double buffer

    // ---- layer 0: 1 -> 128 (1 KB coalesced read) ----
    {
        const float xv = x[b];
        float a0 = wb[lane]      * xv + wb[128 + lane];
        float a1 = wb[64 + lane] * xv + wb[192 + lane];
        yb[0][lane]      = silu(a0);
        yb[0][64 + lane] = silu(a1);
    }
    lds_fence();

    int idx = 2 * WIDTH;
    int cur = 0;

    // ---- hidden layers 1..3: 128 x 128 + SiLU ----
    #pragma unroll 1
    for (int layer = 0; layer < 3; ++layer) {
        const float* __restrict__ W    = wb + idx;
        const float* __restrict__ bias = W + WIDTH * WIDTH;
        const float* ycur = yb[cur];
        float*       ynxt = yb[cur ^ 1];

        #pragma unroll
        for (int p = 0; p < 16; ++p) {
            const int j = p * 8 + g;                       // output row
            const float4* __restrict__ Wrow = (const float4*)(W + j * WIDTH);
            float a = 0.0f;
            #pragma unroll
            for (int i = 0; i < 4; ++i) {
                const float4 wvv = Wrow[l + i * 8];
                const float4 yv  = *(const float4*)(ycur + l * 4 + i * 32);
                a += wvv.x * yv.x + wvv.y * yv.y + wvv.z * yv.z + wvv.w * yv.w;
            }
            a += __shfl_xor(a, 1);
            a += __shfl_xor(a, 2);
            a += __shfl_xor(a, 4);
            if (l == 0) {
                ynxt[j] = silu(a + bias[j]);
            }
        }
        lds_fence();
        cur ^= 1;
        idx += WIDTH * WIDTH + WIDTH;
    }

    // ---- final layer: 128 -> 64, heads, coalesced store ----
    {
        const float* __restrict__ W    = wb + idx;
        const float* __restrict__ bias = W + OUTD * WIDTH;
        const float* ycur = yb[cur];
        float*       ystg = yb[cur ^ 1];

        #pragma unroll
        for (int p = 0; p < 8; ++p) {
            const int j = p * 8 + g;
            const float4* __restrict__ Wrow = (const float4*)(W + j * WIDTH);
            float a = 0.0f;
            #pragma unroll
            for (int i = 0; i < 4; ++i) {
                const float4 wvv = Wrow[l + i * 8];
                const float4 yv  = *(const float4*)(ycur + l * 4 + i * 32);
                a += wvv.x * yv.x + wvv.y * yv.y + wvv.z * yv.z + wvv.w * yv.w;
            }
            a += __shfl_xor(a, 1);
            a += __shfl_xor(a, 2);
            a += __shfl_xor(a, 4);
            if (l == 0) {
                ystg[j] = a + bias[j];
            }
        }
        lds_fence();

        // all 64 lanes: apply head, coalesced 256B store
        float a = ystg[lane];
        float r;
        if (lane < 32) {
            r = tanhf(a);
        } else {
            float lv = fminf(fmaxf(a, -4.0f), 4.0f);
            r = expf(0.5f * lv);
        }
        out[(size_t)b * OUTD + lane] = r;
    }
}

extern "C" void kernel_launch(void* const* d_in, const int* in_sizes, int n_in,
                              void* d_out, int out_size, void* d_ws, size_t ws_size,
                              hipStream_t stream) {
    const float* x = (const float*)d_in[0];        // (4096, 1)
    const float* w = (const float*)d_in[1];        // (4096, 58048)
    float* out = (float*)d_out;                    // (4096, 64)

    const int batch = in_sizes[0];                 // 4096
    rootmlp_kernel<<<batch / 4, 256, 0, stream>>>(x, w, out);
}

// Round 4
// 146.371 us; speedup vs baseline: 2.9685x; 1.1179x over previous
//
#include <hip/hip_runtime.h>
#include <math.h>

// RootMLP: per-sample MLP  1 -> 128 -> 128 -> 128 -> 128 -> 64
// head: mean = tanh(y[:32]), std = exp(0.5*clip(y[32:], -4, 4))
// flat_weights[b] layout per layer: W (d_out, d_in) row-major, then bias (d_out).
//
// Round-4: round-3 structure (one wave per sample, no block barriers, per-wave
// lgkmcnt-only LDS fences) + NON-TEMPORAL weight loads / output stores.
// The weight stream (951 MB) has zero reuse; nt loads avoid cache-allocation
// churn in L1/L2/L3 on a pure streaming read.
//
// Geometry (the round-2 win, kept): 8 lanes per output row; lane l reads
// float4 at row*512B + l*16 + i*128 -> every wave VMEM instruction covers
// full 128B cache lines only. 3x shfl_xor reduces the 8 partials. LDS y
// reads are same-address broadcasts across groups (conflict-free).

#define WIDTH 128
#define OUTD  64
#define TOTAL_PARAMS 58048

using v4f = __attribute__((ext_vector_type(4))) float;

__device__ __forceinline__ float silu(float a) {
    return a / (1.0f + expf(-a));
}

// Per-wave LDS write->read ordering fence. Does NOT touch vmcnt: outstanding
// global weight loads stay in flight across layer boundaries.
__device__ __forceinline__ void lds_fence() {
    asm volatile("s_waitcnt lgkmcnt(0)" ::: "memory");
}

__global__ __launch_bounds__(256, 4)   // cap VGPR at 128 so 16 waves/CU resident
void rootmlp_kernel(const float* __restrict__ x,
                    const float* __restrict__ w,
                    float* __restrict__ out) {
    const int wv   = threadIdx.x >> 6;   // wave id 0..3 (one sample each)
    const int lane = threadIdx.x & 63;
    const int b    = blockIdx.x * 4 + wv;
    const int l    = lane & 7;           // lane within 8-lane group
    const int g    = lane >> 3;          // group id 0..7
    const float* __restrict__ wb = w + (size_t)b * TOTAL_PARAMS;

    __shared__ __align__(16) float ybuf[4][2][WIDTH];
    float (*yb)[WIDTH] = ybuf[wv];       // this wave's private double buffer

    // ---- layer 0: 1 -> 128 (1 KB coalesced read) ----
    {
        const float xv = x[b];
        float a0 = __builtin_nontemporal_load(wb + lane)      * xv
                 + __builtin_nontemporal_load(wb + 128 + lane);
        float a1 = __builtin_nontemporal_load(wb + 64 + lane) * xv
                 + __builtin_nontemporal_load(wb + 192 + lane);
        yb[0][lane]      = silu(a0);
        yb[0][64 + lane] = silu(a1);
    }
    lds_fence();

    int idx = 2 * WIDTH;
    int cur = 0;

    // ---- hidden layers 1..3: 128 x 128 + SiLU ----
    #pragma unroll 1
    for (int layer = 0; layer < 3; ++layer) {
        const float* __restrict__ W    = wb + idx;
        const float* __restrict__ bias = W + WIDTH * WIDTH;
        const float* ycur = yb[cur];
        float*       ynxt = yb[cur ^ 1];

        #pragma unroll
        for (int p = 0; p < 16; ++p) {
            const int j = p * 8 + g;                       // output row
            const v4f* __restrict__ Wrow = (const v4f*)(W + j * WIDTH);
            float a = 0.0f;
            #pragma unroll
            for (int i = 0; i < 4; ++i) {
                const v4f wvv = __builtin_nontemporal_load(Wrow + l + i * 8);
                const v4f yv  = *(const v4f*)(ycur + l * 4 + i * 32);
                a += wvv[0] * yv[0] + wvv[1] * yv[1] + wvv[2] * yv[2] + wvv[3] * yv[3];
            }
            a += __shfl_xor(a, 1);
            a += __shfl_xor(a, 2);
            a += __shfl_xor(a, 4);
            if (l == 0) {
                ynxt[j] = silu(a + __builtin_nontemporal_load(bias + j));
            }
        }
        lds_fence();
        cur ^= 1;
        idx += WIDTH * WIDTH + WIDTH;
    }

    // ---- final layer: 128 -> 64, heads, coalesced store ----
    {
        const float* __restrict__ W    = wb + idx;
        const float* __restrict__ bias = W + OUTD * WIDTH;
        const float* ycur = yb[cur];
        float*       ystg = yb[cur ^ 1];

        #pragma unroll
        for (int p = 0; p < 8; ++p) {
            const int j = p * 8 + g;
            const v4f* __restrict__ Wrow = (const v4f*)(W + j * WIDTH);
            float a = 0.0f;
            #pragma unroll
            for (int i = 0; i < 4; ++i) {
                const v4f wvv = __builtin_nontemporal_load(Wrow + l + i * 8);
                const v4f yv  = *(const v4f*)(ycur + l * 4 + i * 32);
                a += wvv[0] * yv[0] + wvv[1] * yv[1] + wvv[2] * yv[2] + wvv[3] * yv[3];
            }
            a += __shfl_xor(a, 1);
            a += __shfl_xor(a, 2);
            a += __shfl_xor(a, 4);
            if (l == 0) {
                ystg[j] = a + __builtin_nontemporal_load(bias + j);
            }
        }
        lds_fence();

        // all 64 lanes: apply head, coalesced 256B store
        float a = ystg[lane];
        float r;
        if (lane < 32) {
            r = tanhf(a);
        } else {
            float lv = fminf(fmaxf(a, -4.0f), 4.0f);
            r = expf(0.5f * lv);
        }
        __builtin_nontemporal_store(r, out + (size_t)b * OUTD + lane);
    }
}

extern "C" void kernel_launch(void* const* d_in, const int* in_sizes, int n_in,
                              void* d_out, int out_size, void* d_ws, size_t ws_size,
                              hipStream_t stream) {
    const float* x = (const float*)d_in[0];        // (4096, 1)
    const float* w = (const float*)d_in[1];        // (4096, 58048)
    float* out = (float*)d_out;                    // (4096, 64)

    const int batch = in_sizes[0];                 // 4096
    rootmlp_kernel<<<batch / 4, 256, 0, stream>>>(x, w, out);
}